// Round 10
// baseline (134.108 us; speedup 1.0000x reference)
//
#include <hip/hip_runtime.h>
#include <hip/hip_bf16.h>

#define DM 1024
#define HID 64
#define NSTEP 6
#define RSTEP (1.0f/6.0f)

using short8  = __attribute__((ext_vector_type(8))) short;
using short4v = __attribute__((ext_vector_type(4))) short;
using f32x4   = __attribute__((ext_vector_type(4))) float;

// workspace byte offsets
#define WS_W1P 0          // 1024x64 bf16 packed A-frags (131072 B)
#define WS_W2P 131072     // 64x1024 bf16 packed A-frags (131072 B)
#define WS_GP  262144     // 64x64 bf16 packed A-frags (8192 B)
#define WS_U   270336     // 64 f32  (u = b2 @ W1k)

// LDS byte offsets (total 19200 B)
#define L_H0 0            // H ping  [16][72] bf16, pitch 144 (2304)
#define L_H1 2304         // H pong
#define L_HB 4608         // Hb = (h/6)*Hsum
#define L_B2 6912         // b2 staged f32[1024] (4096)
#define L_GP 11008        // G packed frags staged (8192)
#define LDS_TOTAL 19200
#define HP 144

// LDS-only barrier: order LDS ops, do NOT drain vmcnt — the per-step
// kk2=1 weight loads can be issued early and stay in flight across
// stage barriers, landing before P6 consumes them.
#define BAR() asm volatile("s_waitcnt lgkmcnt(0)\n\ts_barrier" ::: "memory")

__device__ __forceinline__ short f2bf(float f) {   // RNE via HW cvt
    __hip_bfloat16 h = __float2bfloat16(f);
    short s;
    __builtin_memcpy(&s, &h, 2);
    return s;
}
__device__ __forceinline__ float ftanh(float x) {
    x = fminf(fmaxf(x, -10.f), 10.f);
    float e = __expf(2.f * x);
    return __fdividef(e - 1.f, e + 1.f);
}

// ---------------- prep: pack weights to MFMA fragment layout ----------------
// A-frag layout for mfma_f32_16x16x32_bf16: lane l holds M-row (l&15),
// k = (l>>4)*8 + i (8 consecutive k). Packed so each lane loads one short8.
__global__ void k_prep(const float* __restrict__ W1, const float* __restrict__ W2,
                       const float* __restrict__ b2,
                       short* __restrict__ W1P, short* __restrict__ W2P,
                       short* __restrict__ GP, float* __restrict__ U) {
    __shared__ float red[4][64];
    int b = blockIdx.x;
    int t = threadIdx.x;           // 256 threads
    int l = t & 63, q4 = t >> 6;
    if (b < 128) {                 // W1k (1024x64) -> W1P[kk<32][c<4][l][8]
        if (t < 64) {
            int kk = b >> 2, c = b & 3;
            int col = c * 16 + (l & 15);
            int kb = kk * 32 + ((l >> 4) << 3);
            short8 v;
            #pragma unroll
            for (int i = 0; i < 8; ++i) v[i] = f2bf(W1[(kb + i) * HID + col]);
            *(short8*)(W1P + (((kk * 4 + c) * 64) + l) * 8) = v;
        }
    } else if (b < 256) {          // W2 (64x1024) -> W2P[kk2<2][ct<64][l][8]
        if (t < 64) {
            int bb = b - 128;
            int kk2 = bb >> 6, ct = bb & 63;
            int col = ct * 16 + (l & 15);
            int kb = kk2 * 32 + ((l >> 4) << 3);
            short8 v;
            #pragma unroll
            for (int i = 0; i < 8; ++i) v[i] = f2bf(W2[(kb + i) * DM + col]);
            *(short8*)(W2P + (((kk2 * 64 + ct) * 64) + l) * 8) = v;
        }
    } else if (b < 320) {          // G[j][i] = sum_d W2[j][d]*W1[d][i]; j = b-256
        int j = b - 256;
        float acc = 0.f;
        #pragma unroll 8
        for (int d = q4 * 256; d < q4 * 256 + 256; ++d)
            acc += W2[j * DM + d] * W1[d * HID + l];
        red[q4][l] = acc;
        __syncthreads();
        if (t < 64) {
            float a = red[0][l] + red[1][l] + red[2][l] + red[3][l];
            int kk = j >> 5, lk = (j >> 3) & 3, ii = j & 7, c = l >> 4, lo = l & 15;
            GP[(((kk * 4 + c) * 64) + lk * 16 + lo) * 8 + ii] = f2bf(a);
        }
    } else {                       // u[i] = sum_d b2[d]*W1[d][i]
        float acc = 0.f;
        #pragma unroll 8
        for (int d = q4 * 256; d < q4 * 256 + 256; ++d)
            acc += b2[d] * W1[d * HID + l];
        red[q4][l] = acc;
        __syncthreads();
        if (t < 64) U[l] = red[0][l] + red[1][l] + red[2][l] + red[3][l];
    }
}

// ---------------- fused RK4 neural-ODE kernel ----------------
// Block: 512 thr (8 waves), 16 rows, grid 1024, 2 blocks/CU co-resident.
// Incremental sz: sz' = sz + Hb@G + h*u; GEMM1 once in prologue (w<4).
// STAGE duty: waves 0-3 only (cw=w): rows l15, hid cols cw*16+hq*4
//   (R7's proven 4-wave structure); waves 4-7 wait at the 4 barriers.
// P6: ALL 8 waves; wave w owns cols [w*128,+128) for the 16 rows:
//   lane = row l15 x 32 cols -> z[8] f32x4 = 32 VGPRs (half of R9).
//   The kk2=0 half of the wave's W2 frags is PINNED in 32 VGPRs
//   (loop-invariant, loaded once) -> only 8 inline L2 loads per step,
//   and MFMA starts immediately on the pinned half.
// hb frags double as the sz-update B-operand (srow == l15) — no extra
// reads. MFMA: A = packed weights (M = out-col), B = z/H rows (N = row).
// ALLOCATION: amdgpu_waves_per_eu(2,4) is the only attr the allocator
// honors at VGPR=128 without spilling (9-round ledger).
__global__ __launch_bounds__(512) __attribute__((amdgpu_waves_per_eu(2, 4)))
void k_ode(
        const float* __restrict__ X, const float* __restrict__ W1,
        const float* __restrict__ b1, const float* __restrict__ b2,
        const short* __restrict__ W1P, const short* __restrict__ W2P,
        const short* __restrict__ GP, const float* __restrict__ U,
        float* __restrict__ OUT) {
    extern __shared__ char smem[];
    const int t = threadIdx.x;
    const int lane = t & 63;
    const int w = t >> 6;                    // 0..7
    const int cw = w & 3;                    // stage col-tile (valid for w<4)
    const int hq = lane >> 4;
    const int l15 = lane & 15;
    const int hcol0 = cw * 16 + hq * 4;      // stage hid-col base (in-bounds)
    const size_t row0 = (size_t)blockIdx.x * 16;

    // stage b2 + G into LDS (first dependent read is after BAR #1)
    if (t < 256) *(f32x4*)(smem + L_B2 + t * 16) = *(const f32x4*)(b2 + t * 4);
    *(f32x4*)(smem + L_GP + t * 16) = *(const f32x4*)((const float*)GP + t * 4);

    // per-lane stage constants (only used by w<4; cw keeps reads in-bounds)
    f32x4 u4   = *(const f32x4*)(U + hcol0);
    f32x4 b14  = *(const f32x4*)(b1 + hcol0);
    f32x4 w1t4 = *(const f32x4*)(W1 + DM * HID + hcol0);   // time row of W1

    // ---- z master: lane owns row l15, cols w*128 + qc*16 + hq*4 ----
    f32x4 z[8];
    {
        const float* zr = X + (row0 + l15) * DM + w * 128;
        #pragma unroll
        for (int qc = 0; qc < 8; ++qc)
            z[qc] = *(const f32x4*)(zr + qc * 16 + hq * 4);
    }

    // ---- pinned W2 frags (kk2=0 half): loop-invariant, loaded once ----
    const short8* w2p8 = (const short8*)W2P;
    short8 wpin[8];
    #pragma unroll
    for (int qc = 0; qc < 8; ++qc)
        wpin[qc] = w2p8[(w * 8 + qc) * 64 + lane];

    // ---- prologue GEMM1 (once, w<4): sz = x @ W1k for stage tile ----
    f32x4 sz = (f32x4){0.f, 0.f, 0.f, 0.f};
    if (w < 4) {
        const float* xrow = X + (row0 + l15) * DM;
        const short8* wp = (const short8*)W1P + (cw * 64 + lane);
        f32x4 a0 = (f32x4){0.f, 0.f, 0.f, 0.f};
        f32x4 a1 = (f32x4){0.f, 0.f, 0.f, 0.f};
        #pragma unroll 4
        for (int kk = 0; kk < 32; kk += 2) {
            const float* xp = xrow + (kk << 5) + (hq << 3);
            f32x4 lo0 = *(const f32x4*)(xp);
            f32x4 hi0 = *(const f32x4*)(xp + 4);
            f32x4 lo1 = *(const f32x4*)(xp + 32);
            f32x4 hi1 = *(const f32x4*)(xp + 36);
            short8 zf0, zf1;
            #pragma unroll
            for (int j = 0; j < 4; ++j) {
                zf0[j] = f2bf(lo0[j]); zf0[4 + j] = f2bf(hi0[j]);
                zf1[j] = f2bf(lo1[j]); zf1[4 + j] = f2bf(hi1[j]);
            }
            a0 = __builtin_amdgcn_mfma_f32_16x16x32_bf16(wp[kk * 256],       zf0, a0, 0, 0, 0);
            a1 = __builtin_amdgcn_mfma_f32_16x16x32_bf16(wp[(kk + 1) * 256], zf1, a1, 0, 0, 0);
        }
        sz = a0 + a1;
    }

    for (int s = 0; s < NSTEP; ++s) {
        const float tcur = RSTEP * (float)s;
        f32x4 hsum = (f32x4){0.f, 0.f, 0.f, 0.f};

        // stage 1 (w<4): H1 = tanh(sz + t*w1t + b1) -> H0
        if (w < 4) {
            short4v hc;
            #pragma unroll
            for (int j = 0; j < 4; ++j) {
                float T = sz[j] + tcur * w1t4[j] + b14[j];
                float h = ftanh(T);
                hsum[j] = h;
                hc[j] = f2bf(h);
            }
            *(short4v*)(smem + L_H0 + l15 * HP + hcol0 * 2) = hc;
        }
        BAR();

        // stages 2..4 (w<4) via tiny H@G GEMM (G frags from LDS)
        #pragma unroll
        for (int st = 0; st < 3; ++st) {
            if (w < 4) {
                const float c_i = (st == 2) ? RSTEP : (0.5f * RSTEP);
                const float t_i = tcur + ((st == 2) ? RSTEP : (0.5f * RSTEP));
                const float w_i = (st == 2) ? 1.f : 2.f;
                const int rbuf = (st & 1) ? L_H1 : L_H0;
                const int wbuf = (st & 1) ? L_H0 : L_H1;

                short8 hf0 = *(const short8*)(smem + rbuf + l15 * HP + (hq << 4));
                short8 hf1 = *(const short8*)(smem + rbuf + l15 * HP + 64 + (hq << 4));
                short8 gf0 = *(const short8*)(smem + L_GP + (cw * 64 + lane) * 16);
                short8 gf1 = *(const short8*)(smem + L_GP + ((4 + cw) * 64 + lane) * 16);
                f32x4 dd = (f32x4){0.f, 0.f, 0.f, 0.f};
                dd = __builtin_amdgcn_mfma_f32_16x16x32_bf16(gf0, hf0, dd, 0, 0, 0);
                dd = __builtin_amdgcn_mfma_f32_16x16x32_bf16(gf1, hf1, dd, 0, 0, 0);
                short4v hc;
                #pragma unroll
                for (int j = 0; j < 4; ++j) {
                    float T = sz[j] + c_i * (dd[j] + u4[j]) + t_i * w1t4[j] + b14[j];
                    float h = ftanh(T);
                    hsum[j] += w_i * h;
                    hc[j] = f2bf(h);
                }
                if (st < 2) {
                    *(short4v*)(smem + wbuf + l15 * HP + hcol0 * 2) = hc;
                } else {   // Hb = (h/6) * Hsum
                    short4v hb4;
                    #pragma unroll
                    for (int j = 0; j < 4; ++j) hb4[j] = f2bf(hsum[j] * (RSTEP / 6.f));
                    *(short4v*)(smem + L_HB + l15 * HP + hcol0 * 2) = hb4;
                }
            }
            BAR();
        }

        // P6 (all 8 waves, barrier-free): z += Hb @ W2 + h*b2 on cols
        // [w*128,+128); kk2=0 from pinned regs, kk2=1 inline (8 loads).
        {
            short8 hb0 = *(const short8*)(smem + L_HB + l15 * HP + (hq << 4));
            short8 hb1 = *(const short8*)(smem + L_HB + l15 * HP + 64 + (hq << 4));

            if (s < NSTEP - 1) {
                #pragma unroll
                for (int qc = 0; qc < 8; ++qc) {
                    int ct = w * 8 + qc;
                    short8 wb = w2p8[(64 + ct) * 64 + lane];
                    f32x4 b2v = *(const f32x4*)(smem + L_B2 + ct * 64 + (hq << 4));
                    f32x4 p = (f32x4){0.f, 0.f, 0.f, 0.f};
                    p = __builtin_amdgcn_mfma_f32_16x16x32_bf16(wpin[qc], hb0, p, 0, 0, 0);
                    p = __builtin_amdgcn_mfma_f32_16x16x32_bf16(wb,       hb1, p, 0, 0, 0);
                    #pragma unroll
                    for (int j = 0; j < 4; ++j)
                        z[qc][j] += p[j] + RSTEP * b2v[j];
                }
                // incremental sz update (w<4): reuses hb0/hb1 (srow == l15)
                if (w < 4) {
                    short8 gf0 = *(const short8*)(smem + L_GP + (cw * 64 + lane) * 16);
                    short8 gf1 = *(const short8*)(smem + L_GP + ((4 + cw) * 64 + lane) * 16);
                    f32x4 d = (f32x4){0.f, 0.f, 0.f, 0.f};
                    d = __builtin_amdgcn_mfma_f32_16x16x32_bf16(gf0, hb0, d, 0, 0, 0);
                    d = __builtin_amdgcn_mfma_f32_16x16x32_bf16(gf1, hb1, d, 0, 0, 0);
                    #pragma unroll
                    for (int j = 0; j < 4; ++j)
                        sz[j] += d[j] + RSTEP * u4[j];
                }
            } else {   // last step: final z straight from regs to OUT (f32)
                float* orow = OUT + (row0 + l15) * DM + w * 128;
                #pragma unroll
                for (int qc = 0; qc < 8; ++qc) {
                    int ct = w * 8 + qc;
                    short8 wb = w2p8[(64 + ct) * 64 + lane];
                    f32x4 b2v = *(const f32x4*)(smem + L_B2 + ct * 64 + (hq << 4));
                    f32x4 p = (f32x4){0.f, 0.f, 0.f, 0.f};
                    p = __builtin_amdgcn_mfma_f32_16x16x32_bf16(wpin[qc], hb0, p, 0, 0, 0);
                    p = __builtin_amdgcn_mfma_f32_16x16x32_bf16(wb,       hb1, p, 0, 0, 0);
                    f32x4 nv;
                    #pragma unroll
                    for (int j = 0; j < 4; ++j)
                        nv[j] = z[qc][j] + p[j] + RSTEP * b2v[j];
                    *(f32x4*)(orow + qc * 16 + hq * 4) = nv;
                }
            }
        }
        // no barrier: next stage1 writes H0 only; all waves already passed
        // the stage-4 barrier (H0's last reader); P6 reads only L_HB/L_B2.
    }
}

extern "C" void kernel_launch(void* const* d_in, const int* in_sizes, int n_in,
                              void* d_out, int out_size, void* d_ws, size_t ws_size,
                              hipStream_t stream) {
    (void)in_sizes; (void)n_in; (void)out_size; (void)ws_size;
    const float* X  = (const float*)d_in[0];
    const float* W1 = (const float*)d_in[1];
    const float* b1 = (const float*)d_in[2];
    const float* W2 = (const float*)d_in[3];
    const float* b2 = (const float*)d_in[4];
    float* OUT = (float*)d_out;
    short* W1P = (short*)((char*)d_ws + WS_W1P);
    short* W2P = (short*)((char*)d_ws + WS_W2P);
    short* GP  = (short*)((char*)d_ws + WS_GP);
    float* U   = (float*)((char*)d_ws + WS_U);

    k_prep<<<321, 256, 0, stream>>>(W1, W2, b2, W1P, W2P, GP, U);
    k_ode<<<1024, 512, LDS_TOTAL, stream>>>(X, W1, b1, b2, W1P, W2P, GP, U, OUT);
}